// Round 7
// baseline (929.576 us; speedup 1.0000x reference)
//
#include <hip/hip_runtime.h>
#include <math.h>

// Problem constants (B=2, S=4096, D=512, MAXC=32, BIAS_LEN=128, TEMP=1)
#define BB   2
#define SS   4096
#define DD   512
#define DH   256      // D/2
#define KTOP 32
#define HALF 2048     // j processed in two halves to bound workspace
#define SCALE 0.044194173824159216f   // 1/sqrt(512)

// decode row of triangular tile list: q in [0, r_max*(r_max+1)/2)
__device__ __forceinline__ int tri_row(int q) {
    int r = (int)((sqrtf(8.0f * q + 1.0f) - 1.0f) * 0.5f);
    while ((r + 1) * (r + 2) / 2 <= q) ++r;
    while (r * (r + 1) / 2 > q) --r;
    return r;
}

// ---------------------------------------------------------------------------
// MLP GEMM: C[M,N] = act(A @ W + bias), 64x64 tile, 4x4 micro.
// v7: float4 global loads + register prefetch; inner-loop arithmetic order
// IDENTICAL to R3 (bitwise-same outputs).
// ---------------------------------------------------------------------------
template<bool GELU>
__global__ __launch_bounds__(256)
void gemm_bias_act(const float* __restrict__ A, const float* __restrict__ W,
                   const float* __restrict__ bias, float* __restrict__ C,
                   int M, int N, int K)
{
    __shared__ float As[16][68];   // [k][m]
    __shared__ float Ws[16][68];   // [k][n]
    const int t  = threadIdx.x;
    const int tn = t & 15;
    const int tm = t >> 4;
    const int n0 = blockIdx.x * 64;
    const int m0 = blockIdx.y * 64;

    const int am = t >> 2, aq = t & 3;           // A stager: row, k-quad
    const int wk = t >> 4, wn4 = (t & 15) * 4;   // W stager: k-row, n-quad
    const float* Ap = A + (size_t)(m0 + am) * K + aq * 4;
    const float* Wp = W + (size_t)wk * N + n0 + wn4;

    float acc[4][4] = {};
    float4 pa = *(const float4*)Ap;              // chunk 0 prefetch
    float4 pw = *(const float4*)Wp;

    for (int k0 = 0; k0 < K; k0 += 16) {
        __syncthreads();
        As[aq * 4 + 0][am] = pa.x; As[aq * 4 + 1][am] = pa.y;
        As[aq * 4 + 2][am] = pa.z; As[aq * 4 + 3][am] = pa.w;
        *(float4*)&Ws[wk][wn4] = pw;
        __syncthreads();
        if (k0 + 16 < K) {
            pa = *(const float4*)(Ap + k0 + 16);
            pw = *(const float4*)(Wp + (size_t)(k0 + 16) * N);
        }
        #pragma unroll
        for (int kk = 0; kk < 16; ++kk) {
            float4 a = *(const float4*)&As[kk][tm * 4];
            float4 w = *(const float4*)&Ws[kk][tn * 4];
            float av[4] = {a.x, a.y, a.z, a.w};
            float wv[4] = {w.x, w.y, w.z, w.w};
            #pragma unroll
            for (int i = 0; i < 4; ++i)
                #pragma unroll
                for (int j = 0; j < 4; ++j)
                    acc[i][j] = fmaf(av[i], wv[j], acc[i][j]);
        }
    }

    #pragma unroll
    for (int i = 0; i < 4; ++i) {
        float4 o;
        #pragma unroll
        for (int j = 0; j < 4; ++j) {
            float v = acc[i][j] + bias[n0 + tn * 4 + j];
            if (GELU) v = 0.5f * v * (1.0f + erff(v * 0.7071067811865475f));
            (&o.x)[j] = v;
        }
        *(float4*)&C[(size_t)(m0 + tm * 4 + i) * N + (n0 + tn * 4)] = o;
    }
}

// ---------------------------------------------------------------------------
// Scores GEMM (fp32, bitwise-identical arithmetic to R3): 128x128 tile,
// 4 waves (2x2), 8x8 lane grid, 8x8 micro. Conflict-free LDS reads
// (8 distinct addrs x 8-lane broadcast = 2/bank). Live-tile-only grid:
// h=0: id<256 rect (rt 16..31 x jt 0..15) else triangular rt 0..15;
// h=1: triangular rt 16..31, jt 16..rt.
// ---------------------------------------------------------------------------
__global__ __launch_bounds__(256, 2)
void scores_gemm(const float* __restrict__ A, const float* __restrict__ Bm,
                 const float* __restrict__ lb, float* __restrict__ Sc, int h)
{
    __shared__ float As[32][132];
    __shared__ float Bs[32][132];
    const int t = threadIdx.x;

    int rt, jtl, jtg;
    {
        int id = blockIdx.x;
        if (h == 0) {
            if (id < 256) { rt = 16 + (id >> 4); jtl = id & 15; }
            else { int q = id - 256; rt = tri_row(q); jtl = q - rt * (rt + 1) / 2; }
            jtg = jtl;
        } else {
            int r = tri_row(id); rt = 16 + r;
            jtl = id - r * (r + 1) / 2; jtg = jtl + 16;
        }
    }
    const int b  = blockIdx.z;
    const int i0 = rt << 7, j0 = jtg << 7;
    const size_t bo = (size_t)b * SS * DD;
    const float* Ab = A  + bo + (size_t)i0 * DD;
    const float* Bb = Bm + bo + (size_t)j0 * DD;

    const int kq = t & 7;        // stager: k-quad within chunk
    const int rr = t >> 3;       // stager: 0..31
    const int lane = t & 63, wav = t >> 6;
    const int wr = wav >> 1, wc = wav & 1;       // wave 2x2 over 64x64 regions
    const int li = lane >> 3, lj = lane & 7;     // 8x8 lane grid

    float acc[8][8] = {};
    float4 aR[4], bR[4];
    #pragma unroll
    for (int u = 0; u < 4; ++u) {                // prologue: chunk 0 -> regs
        int r = u * 32 + rr;
        aR[u] = *(const float4*)&Ab[(size_t)r * DD + 4 * kq];
        bR[u] = *(const float4*)&Bb[(size_t)r * DD + 4 * kq];
    }
    for (int c = 0; c < 16; ++c) {
        __syncthreads();
        #pragma unroll
        for (int u = 0; u < 4; ++u) {            // regs -> LDS (transposed [k][m])
            int r = u * 32 + rr;
            As[4*kq+0][r] = aR[u].x; As[4*kq+1][r] = aR[u].y;
            As[4*kq+2][r] = aR[u].z; As[4*kq+3][r] = aR[u].w;
            Bs[4*kq+0][r] = bR[u].x; Bs[4*kq+1][r] = bR[u].y;
            Bs[4*kq+2][r] = bR[u].z; Bs[4*kq+3][r] = bR[u].w;
        }
        __syncthreads();
        if (c + 1 < 16) {                        // prefetch next chunk -> regs
            int k0 = (c + 1) * 32;
            #pragma unroll
            for (int u = 0; u < 4; ++u) {
                int r = u * 32 + rr;
                aR[u] = *(const float4*)&Ab[(size_t)r * DD + k0 + 4 * kq];
                bR[u] = *(const float4*)&Bb[(size_t)r * DD + k0 + 4 * kq];
            }
        }
        #pragma unroll
        for (int kk = 0; kk < 32; ++kk) {        // conflict-free: 8 addrs x 8-bcast
            float4 a0 = *(const float4*)&As[kk][wr * 64 + li * 8];
            float4 a1 = *(const float4*)&As[kk][wr * 64 + li * 8 + 4];
            float4 b0 = *(const float4*)&Bs[kk][wc * 64 + lj * 8];
            float4 b1 = *(const float4*)&Bs[kk][wc * 64 + lj * 8 + 4];
            float av[8] = {a0.x,a0.y,a0.z,a0.w,a1.x,a1.y,a1.z,a1.w};
            float bv[8] = {b0.x,b0.y,b0.z,b0.w,b1.x,b1.y,b1.z,b1.w};
            #pragma unroll
            for (int ri = 0; ri < 8; ++ri)
                #pragma unroll
                for (int rj = 0; rj < 8; ++rj)
                    acc[ri][rj] = fmaf(av[ri], bv[rj], acc[ri][rj]);
        }
    }

    const bool farTile = (i0 - j0) >= 256;       // whole tile has rel <= -64
    const float lb0 = lb[0];
    #pragma unroll
    for (int ri = 0; ri < 8; ++ri) {
        int i = i0 + wr * 64 + li * 8 + ri;
        size_t rbase = ((size_t)b * SS + i) * HALF + (jtl << 7) + wc * 64 + lj * 8;
        float o[8];
        #pragma unroll
        for (int rj = 0; rj < 8; ++rj) {
            int j = j0 + wc * 64 + lj * 8 + rj;
            float v = acc[ri][rj] * SCALE;
            if (farTile) v += lb0;
            else {
                int rel = j - i;                       // in [-255, 127]
                int bi  = rel < -64 ? 0 : rel + 64;    // clip(rel,-64,63)+64
                v += lb[min(bi, 127)];
                if (rel > 0) v = -INFINITY;            // causal
            }
            o[rj] = v;
        }
        *(float4*)&Sc[rbase]     = make_float4(o[0],o[1],o[2],o[3]);
        *(float4*)&Sc[rbase + 4] = make_float4(o[4],o[5],o[6],o[7]);
    }
}

// ---------------------------------------------------------------------------
// Top-k: one wave per row (unchanged, verified R3).
// ---------------------------------------------------------------------------
__global__ __launch_bounds__(256)
void topk_rows(const float* __restrict__ Sc,
               const float* __restrict__ p0v_in, const int* __restrict__ p0j_in,
               float* __restrict__ p0v_out, int* __restrict__ p0j_out,
               float* __restrict__ out, int h)
{
    __shared__ float mv[4][64];
    __shared__ int   mj[4][64];
    __shared__ float sOv[4][32];
    __shared__ int   sOj[4][32];

    const int lane = threadIdx.x & 63;
    const int w    = threadIdx.x >> 6;
    const int wid  = blockIdx.x * 4 + w;
    int b, i;
    if (h == 0) { b = wid >> 12; i = wid & 4095; }
    else        { b = wid >> 11; i = HALF + (wid & 2047); }
    const int nv = (h == 0) ? min(i + 1, HALF) : (i + 1 - HALF);
    const size_t rb = ((size_t)b * SS + i) * HALF;
    const int l4 = lane * 4;

    float val[32];
    #pragma unroll
    for (int s = 0; s < 8; ++s) {
        int jb = s * 256 + l4;
        float4 f = make_float4(-INFINITY, -INFINITY, -INFINITY, -INFINITY);
        if (jb < nv) f = *(const float4*)&Sc[rb + jb];
        val[4*s+0] = (jb + 0 < nv) ? f.x : -INFINITY;
        val[4*s+1] = (jb + 1 < nv) ? f.y : -INFINITY;
        val[4*s+2] = (jb + 2 < nv) ? f.z : -INFINITY;
        val[4*s+3] = (jb + 3 < nv) ? f.w : -INFINITY;
    }

    unsigned dead = 0;
    float Lv; int Lj, Lc;
    auto localmax = [&]() {
        Lv = -INFINITY; Lj = 0x7fffffff; Lc = 0;
        #pragma unroll
        for (int c = 0; c < 32; ++c) {
            int jh = (c >> 2) * 256 + l4 + (c & 3);
            bool alive = !((dead >> c) & 1u);
            bool bet = alive && (val[c] > Lv || (val[c] == Lv && jh < Lj));
            if (bet) { Lv = val[c]; Lj = jh; Lc = c; }
        }
    };
    localmax();

    float selv = -INFINITY; int selj = 0;
    for (int r = 0; r < KTOP; ++r) {
        float bv = Lv; int bj = Lj;
        #pragma unroll
        for (int m = 1; m < 64; m <<= 1) {
            float ov = __shfl_xor(bv, m, 64);
            int   oj = __shfl_xor(bj, m, 64);
            if (ov > bv || (ov == bv && oj < bj)) { bv = ov; bj = oj; }
        }
        if (lane == r) { selv = bv; selj = bj + h * HALF; }
        if (bj == Lj) { dead |= (1u << Lc); localmax(); }
    }

    if (h == 0 && i >= HALF) {
        if (lane < KTOP) {
            size_t pb = ((size_t)b * HALF + (i - HALF)) * KTOP + lane;
            p0v_out[pb] = selv; p0j_out[pb] = selj;
        }
        return;
    }

    if (h == 1) {
        float p0v = 0.f; int p0j = 0;
        if (lane < KTOP) {
            size_t pb = ((size_t)b * HALF + (i - HALF)) * KTOP + lane;
            p0v = p0v_in[pb]; p0j = p0j_in[pb];
            mv[w][lane] = p0v;         mj[w][lane] = p0j;
            mv[w][KTOP + lane] = selv; mj[w][KTOP + lane] = selj;
        }
        __syncthreads();
        int r0 = 0, r1 = 0;
        if (lane < KTOP) {
            for (int f = 0; f < 64; ++f) {
                float fv = mv[w][f]; int fj = mj[w][f];
                r0 += (fv > p0v || (fv == p0v && fj < p0j)) ? 1 : 0;
                r1 += (fv > selv || (fv == selv && fj < selj)) ? 1 : 0;
            }
        }
        __syncthreads();
        if (lane < KTOP) {
            if (r0 < KTOP) { sOv[w][r0] = p0v;  sOj[w][r0] = p0j;  }
            if (r1 < KTOP) { sOv[w][r1] = selv; sOj[w][r1] = selj; }
        }
        __syncthreads();
        if (lane < KTOP) { selv = sOv[w][lane]; selj = sOj[w][lane]; }
    }

    float mx = __shfl(selv, 0, 64);
    float e  = (lane < KTOP) ? expf(selv - mx) : 0.f;
    float sum = e;
    #pragma unroll
    for (int m = 1; m < 64; m <<= 1) sum += __shfl_xor(sum, m, 64);
    float invs = 1.0f / sum;
    if (lane < KTOP) {
        size_t ob = ((size_t)b * SS + i) * KTOP + lane;
        out[ob] = (float)selj;
        out[(size_t)BB * SS * KTOP + ob] = e * invs;
    }
}

// ---------------------------------------------------------------------------
extern "C" void kernel_launch(void* const* d_in, const int* in_sizes, int n_in,
                              void* d_out, int out_size, void* d_ws, size_t ws_size,
                              hipStream_t stream)
{
    const float* x   = (const float*)d_in[0];
    const float* Wi1 = (const float*)d_in[1];
    const float* bi1 = (const float*)d_in[2];
    const float* Wi2 = (const float*)d_in[3];
    const float* bi2 = (const float*)d_in[4];
    const float* Wf1 = (const float*)d_in[5];
    const float* bf1 = (const float*)d_in[6];
    const float* Wf2 = (const float*)d_in[7];
    const float* bf2 = (const float*)d_in[8];
    const float* lb  = (const float*)d_in[9];
    // d_in[10..13] = adaptive-k MLP (unused for outputs); d_in[14] = mask (all ones)

    const size_t NF = (size_t)BB * SS * DD;          // 4,194,304 floats
    float* ws       = (float*)d_ws;                  // total ~109 MB (R3-verified)
    float* intents  = ws;                            // NF
    float* features = ws + NF;                       // NF
    float* Hbuf     = ws + 2 * NF;                   // NF/2 (MLP scratch)
    float* part0v   = Hbuf;                          // reused after MLPs
    int*   part0j   = (int*)(Hbuf + (size_t)BB * HALF * KTOP);
    float* Sc       = ws + 2 * NF + NF / 2;          // BB*SS*HALF floats (67 MB)

    const int M = BB * SS;  // 8192

    gemm_bias_act<true ><<<dim3(DH / 64, M / 64), 256, 0, stream>>>(x,    Wi1, bi1, Hbuf,     M, DH, DD);
    gemm_bias_act<false><<<dim3(DD / 64, M / 64), 256, 0, stream>>>(Hbuf, Wi2, bi2, intents,  M, DD, DH);
    gemm_bias_act<true ><<<dim3(DH / 64, M / 64), 256, 0, stream>>>(x,    Wf1, bf1, Hbuf,     M, DH, DD);
    gemm_bias_act<false><<<dim3(DD / 64, M / 64), 256, 0, stream>>>(Hbuf, Wf2, bf2, features, M, DD, DH);

    // half 0: j in [0,2048); live tiles only (256 rect + 136 tri)
    scores_gemm<<<dim3(392, 1, BB), 256, 0, stream>>>(intents, features, lb, Sc, 0);
    topk_rows<<<(BB * SS) / 4, 256, 0, stream>>>(Sc, part0v, part0j, part0v, part0j,
                                                 (float*)d_out, 0);
    // half 1: j in [2048,4096), rows >= 2048; 136 tri tiles
    scores_gemm<<<dim3(136, 1, BB), 256, 0, stream>>>(intents, features, lb, Sc, 1);
    topk_rows<<<(BB * HALF) / 4, 256, 0, stream>>>(Sc, part0v, part0j, part0v, part0j,
                                                   (float*)d_out, 1);
}

// Round 8
// 888.425 us; speedup vs baseline: 1.0463x; 1.0463x over previous
//
#include <hip/hip_runtime.h>
#include <math.h>

// Problem constants (B=2, S=4096, D=512, MAXC=32, BIAS_LEN=128, TEMP=1)
#define BB   2
#define SS   4096
#define DD   512
#define DH   256      // D/2
#define KTOP 32
#define HALF 2048     // j processed in two halves to bound workspace
#define SCALE 0.044194173824159216f   // 1/sqrt(512)

// decode row of triangular tile list: q in [0, r_max*(r_max+1)/2)
__device__ __forceinline__ int tri_row(int q) {
    int r = (int)((sqrtf(8.0f * q + 1.0f) - 1.0f) * 0.5f);
    while ((r + 1) * (r + 2) / 2 <= q) ++r;
    while (r * (r + 1) / 2 > q) --r;
    return r;
}

// ---------------------------------------------------------------------------
// MLP GEMM v8: 128x128 tile, 8x8 micro, k-chunks of 32, register prefetch,
// conflict-free LDS reads (8 addrs x 8-lane broadcast). Per-(m,n) arithmetic
// chain (ascending-k fmaf, + bias, exact GELU) is BITWISE-IDENTICAL to the
// R3/R7 kernel — only the parallel structure changed. blockIdx.z fuses the
// intents/features twin GEMMs into one dispatch.
// ---------------------------------------------------------------------------
template<bool GELU>
__global__ __launch_bounds__(256)
void gemm128(const float* __restrict__ A0, const float* __restrict__ A1,
             const float* __restrict__ W0, const float* __restrict__ W1,
             const float* __restrict__ b0, const float* __restrict__ b1,
             float* __restrict__ C0, float* __restrict__ C1,
             int N, int K)
{
    __shared__ float As[32][132];   // [k][m]
    __shared__ float Ws[32][132];   // [k][n]
    const int t = threadIdx.x;
    const int z = blockIdx.z;
    const float* A    = z ? A1 : A0;
    const float* W    = z ? W1 : W0;
    const float* bias = z ? b1 : b0;
    float*       C    = z ? C1 : C0;
    const int n0 = blockIdx.x * 128;
    const int m0 = blockIdx.y * 128;

    const int kq = t & 7;          // A stager: k-quad within chunk
    const int rr = t >> 3;         // A stager: row 0..31 (+u*32)
    const int wkr = t >> 3;        // W stager: k-row 0..31
    const int wnc = (t & 7) * 16;  // W stager: col group (16 cols = 4 float4)
    const float* Ab = A + (size_t)m0 * K;
    const float* Wb = W + (size_t)0 * N + n0;

    const int lane = t & 63, wav = t >> 6;
    const int wr = wav >> 1, wc = wav & 1;     // wave 2x2 over 64x64 regions
    const int li = lane >> 3, lj = lane & 7;   // 8x8 lane grid

    float acc[8][8] = {};
    float4 aR[4], wR[4];
    #pragma unroll
    for (int u = 0; u < 4; ++u) {              // prologue: chunk 0 -> regs
        int r = u * 32 + rr;
        aR[u] = *(const float4*)&Ab[(size_t)r * K + 4 * kq];
        wR[u] = *(const float4*)&Wb[(size_t)wkr * N + wnc + 4 * u];
    }
    const int nch = K >> 5;
    for (int c = 0; c < nch; ++c) {
        __syncthreads();
        #pragma unroll
        for (int u = 0; u < 4; ++u) {          // regs -> LDS
            int r = u * 32 + rr;
            As[4*kq+0][r] = aR[u].x; As[4*kq+1][r] = aR[u].y;
            As[4*kq+2][r] = aR[u].z; As[4*kq+3][r] = aR[u].w;
            *(float4*)&Ws[wkr][wnc + 4 * u] = wR[u];
        }
        __syncthreads();
        if (c + 1 < nch) {                     // prefetch next chunk
            int k0 = (c + 1) * 32;
            #pragma unroll
            for (int u = 0; u < 4; ++u) {
                int r = u * 32 + rr;
                aR[u] = *(const float4*)&Ab[(size_t)r * K + k0 + 4 * kq];
                wR[u] = *(const float4*)&Wb[(size_t)(k0 + wkr) * N + wnc + 4 * u];
            }
        }
        #pragma unroll
        for (int kk = 0; kk < 32; ++kk) {      // conflict-free: 8 addrs x 8-bcast
            float4 a0 = *(const float4*)&As[kk][wr * 64 + li * 8];
            float4 a1 = *(const float4*)&As[kk][wr * 64 + li * 8 + 4];
            float4 b0v = *(const float4*)&Ws[kk][wc * 64 + lj * 8];
            float4 b1v = *(const float4*)&Ws[kk][wc * 64 + lj * 8 + 4];
            float av[8] = {a0.x,a0.y,a0.z,a0.w,a1.x,a1.y,a1.z,a1.w};
            float bv[8] = {b0v.x,b0v.y,b0v.z,b0v.w,b1v.x,b1v.y,b1v.z,b1v.w};
            #pragma unroll
            for (int ri = 0; ri < 8; ++ri)
                #pragma unroll
                for (int rj = 0; rj < 8; ++rj)
                    acc[ri][rj] = fmaf(av[ri], bv[rj], acc[ri][rj]);
        }
    }

    const int nb = n0 + wc * 64 + lj * 8;
    float bv0[8];
    *(float4*)&bv0[0] = *(const float4*)&bias[nb];
    *(float4*)&bv0[4] = *(const float4*)&bias[nb + 4];
    #pragma unroll
    for (int ri = 0; ri < 8; ++ri) {
        int m = m0 + wr * 64 + li * 8 + ri;
        float o[8];
        #pragma unroll
        for (int rj = 0; rj < 8; ++rj) {
            float v = acc[ri][rj] + bv0[rj];   // same op order as R3: acc + bias
            if (GELU) v = 0.5f * v * (1.0f + erff(v * 0.7071067811865475f));
            o[rj] = v;
        }
        *(float4*)&C[(size_t)m * N + nb]     = make_float4(o[0],o[1],o[2],o[3]);
        *(float4*)&C[(size_t)m * N + nb + 4] = make_float4(o[4],o[5],o[6],o[7]);
    }
}

// ---------------------------------------------------------------------------
// Scores GEMM (byte-identical to R7 — passing configuration).
// ---------------------------------------------------------------------------
__global__ __launch_bounds__(256, 2)
void scores_gemm(const float* __restrict__ A, const float* __restrict__ Bm,
                 const float* __restrict__ lb, float* __restrict__ Sc, int h)
{
    __shared__ float As[32][132];
    __shared__ float Bs[32][132];
    const int t = threadIdx.x;

    int rt, jtl, jtg;
    {
        int id = blockIdx.x;
        if (h == 0) {
            if (id < 256) { rt = 16 + (id >> 4); jtl = id & 15; }
            else { int q = id - 256; rt = tri_row(q); jtl = q - rt * (rt + 1) / 2; }
            jtg = jtl;
        } else {
            int r = tri_row(id); rt = 16 + r;
            jtl = id - r * (r + 1) / 2; jtg = jtl + 16;
        }
    }
    const int b  = blockIdx.z;
    const int i0 = rt << 7, j0 = jtg << 7;
    const size_t bo = (size_t)b * SS * DD;
    const float* Ab = A  + bo + (size_t)i0 * DD;
    const float* Bb = Bm + bo + (size_t)j0 * DD;

    const int kq = t & 7;
    const int rr = t >> 3;
    const int lane = t & 63, wav = t >> 6;
    const int wr = wav >> 1, wc = wav & 1;
    const int li = lane >> 3, lj = lane & 7;

    float acc[8][8] = {};
    float4 aR[4], bR[4];
    #pragma unroll
    for (int u = 0; u < 4; ++u) {
        int r = u * 32 + rr;
        aR[u] = *(const float4*)&Ab[(size_t)r * DD + 4 * kq];
        bR[u] = *(const float4*)&Bb[(size_t)r * DD + 4 * kq];
    }
    for (int c = 0; c < 16; ++c) {
        __syncthreads();
        #pragma unroll
        for (int u = 0; u < 4; ++u) {
            int r = u * 32 + rr;
            As[4*kq+0][r] = aR[u].x; As[4*kq+1][r] = aR[u].y;
            As[4*kq+2][r] = aR[u].z; As[4*kq+3][r] = aR[u].w;
            Bs[4*kq+0][r] = bR[u].x; Bs[4*kq+1][r] = bR[u].y;
            Bs[4*kq+2][r] = bR[u].z; Bs[4*kq+3][r] = bR[u].w;
        }
        __syncthreads();
        if (c + 1 < 16) {
            int k0 = (c + 1) * 32;
            #pragma unroll
            for (int u = 0; u < 4; ++u) {
                int r = u * 32 + rr;
                aR[u] = *(const float4*)&Ab[(size_t)r * DD + k0 + 4 * kq];
                bR[u] = *(const float4*)&Bb[(size_t)r * DD + k0 + 4 * kq];
            }
        }
        #pragma unroll
        for (int kk = 0; kk < 32; ++kk) {
            float4 a0 = *(const float4*)&As[kk][wr * 64 + li * 8];
            float4 a1 = *(const float4*)&As[kk][wr * 64 + li * 8 + 4];
            float4 b0 = *(const float4*)&Bs[kk][wc * 64 + lj * 8];
            float4 b1 = *(const float4*)&Bs[kk][wc * 64 + lj * 8 + 4];
            float av[8] = {a0.x,a0.y,a0.z,a0.w,a1.x,a1.y,a1.z,a1.w};
            float bv[8] = {b0.x,b0.y,b0.z,b0.w,b1.x,b1.y,b1.z,b1.w};
            #pragma unroll
            for (int ri = 0; ri < 8; ++ri)
                #pragma unroll
                for (int rj = 0; rj < 8; ++rj)
                    acc[ri][rj] = fmaf(av[ri], bv[rj], acc[ri][rj]);
        }
    }

    const bool farTile = (i0 - j0) >= 256;
    const float lb0 = lb[0];
    #pragma unroll
    for (int ri = 0; ri < 8; ++ri) {
        int i = i0 + wr * 64 + li * 8 + ri;
        size_t rbase = ((size_t)b * SS + i) * HALF + (jtl << 7) + wc * 64 + lj * 8;
        float o[8];
        #pragma unroll
        for (int rj = 0; rj < 8; ++rj) {
            int j = j0 + wc * 64 + lj * 8 + rj;
            float v = acc[ri][rj] * SCALE;
            if (farTile) v += lb0;
            else {
                int rel = j - i;
                int bi  = rel < -64 ? 0 : rel + 64;
                v += lb[min(bi, 127)];
                if (rel > 0) v = -INFINITY;
            }
            o[rj] = v;
        }
        *(float4*)&Sc[rbase]     = make_float4(o[0],o[1],o[2],o[3]);
        *(float4*)&Sc[rbase + 4] = make_float4(o[4],o[5],o[6],o[7]);
    }
}

// ---------------------------------------------------------------------------
// Top-k: one wave per row (unchanged, verified R3/R7).
// ---------------------------------------------------------------------------
__global__ __launch_bounds__(256)
void topk_rows(const float* __restrict__ Sc,
               const float* __restrict__ p0v_in, const int* __restrict__ p0j_in,
               float* __restrict__ p0v_out, int* __restrict__ p0j_out,
               float* __restrict__ out, int h)
{
    __shared__ float mv[4][64];
    __shared__ int   mj[4][64];
    __shared__ float sOv[4][32];
    __shared__ int   sOj[4][32];

    const int lane = threadIdx.x & 63;
    const int w    = threadIdx.x >> 6;
    const int wid  = blockIdx.x * 4 + w;
    int b, i;
    if (h == 0) { b = wid >> 12; i = wid & 4095; }
    else        { b = wid >> 11; i = HALF + (wid & 2047); }
    const int nv = (h == 0) ? min(i + 1, HALF) : (i + 1 - HALF);
    const size_t rb = ((size_t)b * SS + i) * HALF;
    const int l4 = lane * 4;

    float val[32];
    #pragma unroll
    for (int s = 0; s < 8; ++s) {
        int jb = s * 256 + l4;
        float4 f = make_float4(-INFINITY, -INFINITY, -INFINITY, -INFINITY);
        if (jb < nv) f = *(const float4*)&Sc[rb + jb];
        val[4*s+0] = (jb + 0 < nv) ? f.x : -INFINITY;
        val[4*s+1] = (jb + 1 < nv) ? f.y : -INFINITY;
        val[4*s+2] = (jb + 2 < nv) ? f.z : -INFINITY;
        val[4*s+3] = (jb + 3 < nv) ? f.w : -INFINITY;
    }

    unsigned dead = 0;
    float Lv; int Lj, Lc;
    auto localmax = [&]() {
        Lv = -INFINITY; Lj = 0x7fffffff; Lc = 0;
        #pragma unroll
        for (int c = 0; c < 32; ++c) {
            int jh = (c >> 2) * 256 + l4 + (c & 3);
            bool alive = !((dead >> c) & 1u);
            bool bet = alive && (val[c] > Lv || (val[c] == Lv && jh < Lj));
            if (bet) { Lv = val[c]; Lj = jh; Lc = c; }
        }
    };
    localmax();

    float selv = -INFINITY; int selj = 0;
    for (int r = 0; r < KTOP; ++r) {
        float bv = Lv; int bj = Lj;
        #pragma unroll
        for (int m = 1; m < 64; m <<= 1) {
            float ov = __shfl_xor(bv, m, 64);
            int   oj = __shfl_xor(bj, m, 64);
            if (ov > bv || (ov == bv && oj < bj)) { bv = ov; bj = oj; }
        }
        if (lane == r) { selv = bv; selj = bj + h * HALF; }
        if (bj == Lj) { dead |= (1u << Lc); localmax(); }
    }

    if (h == 0 && i >= HALF) {
        if (lane < KTOP) {
            size_t pb = ((size_t)b * HALF + (i - HALF)) * KTOP + lane;
            p0v_out[pb] = selv; p0j_out[pb] = selj;
        }
        return;
    }

    if (h == 1) {
        float p0v = 0.f; int p0j = 0;
        if (lane < KTOP) {
            size_t pb = ((size_t)b * HALF + (i - HALF)) * KTOP + lane;
            p0v = p0v_in[pb]; p0j = p0j_in[pb];
            mv[w][lane] = p0v;         mj[w][lane] = p0j;
            mv[w][KTOP + lane] = selv; mj[w][KTOP + lane] = selj;
        }
        __syncthreads();
        int r0 = 0, r1 = 0;
        if (lane < KTOP) {
            for (int f = 0; f < 64; ++f) {
                float fv = mv[w][f]; int fj = mj[w][f];
                r0 += (fv > p0v || (fv == p0v && fj < p0j)) ? 1 : 0;
                r1 += (fv > selv || (fv == selv && fj < selj)) ? 1 : 0;
            }
        }
        __syncthreads();
        if (lane < KTOP) {
            if (r0 < KTOP) { sOv[w][r0] = p0v;  sOj[w][r0] = p0j;  }
            if (r1 < KTOP) { sOv[w][r1] = selv; sOj[w][r1] = selj; }
        }
        __syncthreads();
        if (lane < KTOP) { selv = sOv[w][lane]; selj = sOj[w][lane]; }
    }

    float mx = __shfl(selv, 0, 64);
    float e  = (lane < KTOP) ? expf(selv - mx) : 0.f;
    float sum = e;
    #pragma unroll
    for (int m = 1; m < 64; m <<= 1) sum += __shfl_xor(sum, m, 64);
    float invs = 1.0f / sum;
    if (lane < KTOP) {
        size_t ob = ((size_t)b * SS + i) * KTOP + lane;
        out[ob] = (float)selj;
        out[(size_t)BB * SS * KTOP + ob] = e * invs;
    }
}

// ---------------------------------------------------------------------------
extern "C" void kernel_launch(void* const* d_in, const int* in_sizes, int n_in,
                              void* d_out, int out_size, void* d_ws, size_t ws_size,
                              hipStream_t stream)
{
    const float* x   = (const float*)d_in[0];
    const float* Wi1 = (const float*)d_in[1];
    const float* bi1 = (const float*)d_in[2];
    const float* Wi2 = (const float*)d_in[3];
    const float* bi2 = (const float*)d_in[4];
    const float* Wf1 = (const float*)d_in[5];
    const float* bf1 = (const float*)d_in[6];
    const float* Wf2 = (const float*)d_in[7];
    const float* bf2 = (const float*)d_in[8];
    const float* lb  = (const float*)d_in[9];
    // d_in[10..13] = adaptive-k MLP (unused for outputs); d_in[14] = mask (all ones)

    const size_t NF = (size_t)BB * SS * DD;          // 4,194,304 floats
    float* ws       = (float*)d_ws;                  // total ~109 MB (R3-verified)
    float* intents  = ws;                            // NF
    float* features = ws + NF;                       // NF
    float* part0v   = ws + 2 * NF;                   // (old Hbuf region)
    int*   part0j   = (int*)(part0v + (size_t)BB * HALF * KTOP);
    float* Sc       = ws + 2 * NF + NF / 2;          // BB*SS*HALF floats (67 MB)
    float* Hi       = Sc;                            // MLP scratch inside Sc area
    float* Hf       = Sc + NF / 2;                   // (used before Sc is written)

    // MLP1 pair (x@W1+b1, GELU): z=0 -> intents path, z=1 -> features path
    gemm128<true ><<<dim3(DH / 128, 64, 2), 256, 0, stream>>>(
        x, x, Wi1, Wf1, bi1, bf1, Hi, Hf, DH, DD);
    // MLP2 pair (H@W2+b2)
    gemm128<false><<<dim3(DD / 128, 64, 2), 256, 0, stream>>>(
        Hi, Hf, Wi2, Wf2, bi2, bf2, intents, features, DD, DH);

    // half 0: j in [0,2048); live tiles only (256 rect + 136 tri)
    scores_gemm<<<dim3(392, 1, BB), 256, 0, stream>>>(intents, features, lb, Sc, 0);
    topk_rows<<<(BB * SS) / 4, 256, 0, stream>>>(Sc, part0v, part0j, part0v, part0j,
                                                 (float*)d_out, 0);
    // half 1: j in [2048,4096), rows >= 2048; 136 tri tiles
    scores_gemm<<<dim3(136, 1, BB), 256, 0, stream>>>(intents, features, lb, Sc, 1);
    topk_rows<<<(BB * HALF) / 4, 256, 0, stream>>>(Sc, part0v, part0j, part0v, part0j,
                                                   (float*)d_out, 1);
}